// Round 16
// baseline (174.933 us; speedup 1.0000x reference)
//
#include <hip/hip_runtime.h>
#include <stdint.h>

// TriXTile: out = (relu((x @ sign(up_w)^T) * up_scale) @ sign(down_w)^T) * down_scale * out_scale
// Round 16: r12 retried with the register budget fixed. GEMM1 = 256x256 tile,
// 1024 thr (16 waves 4x4, 64x64/wave = GEMM2's proven 1:2 read:MFMA shape),
// 2 LDS buffers, 1 barrier/tile. Fix vs r12: __launch_bounds__(1024) (no 2nd
// arg) + per-ks operand loop -> peak live regs ~116 < 128 (unified VGPR+AGPR
// budget at 4 waves/SIMD). r12's spill (VGPR_Count 64, 408MB scratch) is the
// falsifiable signature: WRITE_SIZE must drop to 32MB.
// GEMM2 and prep byte-identical to r15.

#define M_TOK 4096
#define DM 2048
#define DH 8192

typedef __attribute__((ext_vector_type(4))) int i32x4;

#define GLD16(g, l)                                                     \
  __builtin_amdgcn_global_load_lds(                                     \
      (const __attribute__((address_space(1))) void*)(g),               \
      (__attribute__((address_space(3))) void*)(l), 16, 0, 0)

// ---- merged prepass (r9 verbatim) ----
__global__ __launch_bounds__(256) void prep_kernel(
    const float* __restrict__ x, int8_t* __restrict__ xq,
    float* __restrict__ sx, const float* __restrict__ upw,
    int8_t* __restrict__ upq, const float* __restrict__ dnw,
    int8_t* __restrict__ dnq) {
  const int bid = blockIdx.x;
  const int tid = threadIdx.x;
  if (bid < 4096) {
    const int row = bid;
    const float4* xr = (const float4*)(x + (size_t)row * 2048);
    float4 a = xr[tid * 2], b = xr[tid * 2 + 1];
    float m = fmaxf(fmaxf(fmaxf(fabsf(a.x), fabsf(a.y)), fmaxf(fabsf(a.z), fabsf(a.w))),
                    fmaxf(fmaxf(fabsf(b.x), fabsf(b.y)), fmaxf(fabsf(b.z), fabsf(b.w))));
#pragma unroll
    for (int off = 32; off >= 1; off >>= 1) m = fmaxf(m, __shfl_xor(m, off));
    __shared__ float red[4];
    if ((tid & 63) == 0) red[tid >> 6] = m;
    __syncthreads();
    m = fmaxf(fmaxf(red[0], red[1]), fmaxf(red[2], red[3]));
    const float inv = m > 0.f ? 127.f / m : 0.f;
    if (tid == 0) sx[row] = m > 0.f ? m / 127.f : 0.f;
    auto q8 = [&](float v) -> uint32_t {
      float q = rintf(v * inv);
      q = fminf(fmaxf(q, -127.f), 127.f);
      return (uint32_t)(uint8_t)(int8_t)(int)q;
    };
    uint32_t w0 = q8(a.x) | (q8(a.y) << 8) | (q8(a.z) << 16) | (q8(a.w) << 24);
    uint32_t w1 = q8(b.x) | (q8(b.y) << 8) | (q8(b.z) << 16) | (q8(b.w) << 24);
    uint32_t* o = (uint32_t*)(xq + (size_t)row * 2048);
    o[tid * 2] = w0;
    o[tid * 2 + 1] = w1;
  } else {
    const bool is_up = bid < 6144;
    const float* __restrict__ W = is_up ? upw : dnw;
    int8_t* __restrict__ Q = is_up ? upq : dnq;
    const int vb = bid - (is_up ? 4096 : 6144);
    const int n4 = (DH * DM) / 4;
    const int stride = 2048 * 256;
    auto s8 = [](float v) -> uint32_t {
      int s = (v > 0.f) - (v < 0.f);
      return (uint32_t)(uint8_t)(int8_t)s;
    };
    for (int i = vb * 256 + tid; i < n4; i += stride) {
      float4 v = ((const float4*)W)[i];
      ((uint32_t*)Q)[i] = s8(v.x) | (s8(v.y) << 8) | (s8(v.z) << 16) | (s8(v.w) << 24);
    }
  }
}

// ---------------- GEMM1: 256x256 i8, 16 waves (reg-budget-fixed r12) --------
// hq[M,N] = clamp(rint(relu((xq @ upq^T) * ups[col]) / 64), 0, 127) -> i8.
// K=2048B, BK=128B, nt=16, grid 512 (2 sequential blocks/CU).
// 16 waves 4Mx4N, 64x64/wave (8 ds_reads : 16 MFMAs per ks — GEMM2's ratio).
// LDS 2 x 64KB. Per tile: STAGE(t+1)->other buf at top; per-ks {read 8, MFMA
// 16}; sched_barrier; vmcnt(0) (stage retired under ~2.5k cy compute); barrier.
__global__ __launch_bounds__(1024) void gemm1_i8_kernel(
    const int8_t* __restrict__ A, const int8_t* __restrict__ B,
    int8_t* __restrict__ C, const float* __restrict__ ups,
    int M, int N, int K) {
  constexpr int BUFB = 65536;           // A 32KB + B 32KB
  extern __shared__ char smem[];

  const int nbn = N >> 8;
  const int bid = blockIdx.x;
  const int cpx = gridDim.x >> 3;       // grid % 8 == 0
  const int swz = (bid & 7) * cpx + (bid >> 3);
  const int bm = swz / nbn, bn = swz % nbn;

  const int tid = threadIdx.x;
  const int lane = tid & 63;
  const int wv = tid >> 6;              // 0..15
  const int wm = wv >> 2, wn = wv & 3;  // 4 x 4 waves, 64x64 each
  const int lr = lane & 15, lg = lane >> 4;

  // Staging: 4 units of 16KB (A rows 0-127, A 128-255, B 0-127, B 128-255).
  // thread t covers unit byte t*16: srow = t>>3 (0..127), pre-swizzled col.
  const int srow = tid >> 3;
  const int scolB = ((tid & 7) ^ (srow & 7)) << 4;
  const int8_t* aS = A + (size_t)(bm * 256 + srow) * K + scolB;
  const int8_t* bS = B + (size_t)(bn * 256 + srow) * K + scolB;
  const int ldsl = wv * 1024;           // wave-uniform lane-block base

  const int nt = K >> 7;
  i32x4 acc[4][4] = {};

  auto STAGE = [&](int t, int q) {
    char* d = smem + q * BUFB + ldsl;
    const int8_t* a0 = aS + (size_t)t * 128;
    const int8_t* b0 = bS + (size_t)t * 128;
    GLD16(a0, d);                                   // A rows   0..127
    GLD16(a0 + (size_t)128 * K, d + 16384);         // A rows 128..255
    GLD16(b0, d + 32768);                           // B rows   0..127
    GLD16(b0 + (size_t)128 * K, d + 49152);         // B rows 128..255
  };

  // Prologue: tile 0 staged + published.
  STAGE(0, 0);
  asm volatile("s_waitcnt vmcnt(0)" ::: "memory");
  __builtin_amdgcn_s_barrier();

  const int xorv = (lr & 7) << 4;
  const int abase = (wm * 64 + lr) * 128;
  const int bbase = 32768 + (wn * 64 + lr) * 128;

  for (int t = 0; t < nt; ++t) {
    if (t + 1 < nt) STAGE(t + 1, (t + 1) & 1);

    const char* bufc = smem + (t & 1) * BUFB;
    const char* cA = bufc + abase;
    const char* cB = bufc + bbase;

    // per-ks operand loop: peak live = acc 64 + a 16 + b 16 + addr (<128)
#pragma unroll
    for (int ks = 0; ks < 2; ++ks) {
      const int ko = ((ks << 6) + (lg << 4)) ^ xorv;
      i32x4 a[4], b[4];
#pragma unroll
      for (int i = 0; i < 4; ++i) a[i] = *(const i32x4*)(cA + (i << 11) + ko);
#pragma unroll
      for (int j = 0; j < 4; ++j) b[j] = *(const i32x4*)(cB + (j << 11) + ko);

      __builtin_amdgcn_s_setprio(1);
#pragma unroll
      for (int i = 0; i < 4; ++i)
#pragma unroll
        for (int j = 0; j < 4; ++j)
          acc[i][j] = __builtin_amdgcn_mfma_i32_16x16x64_i8(
              a[i], b[j], acc[i][j], 0, 0, 0);
      __builtin_amdgcn_s_setprio(0);
    }

    // Pin ds_read issue above the barrier; stage loads retired under compute.
    __builtin_amdgcn_sched_barrier(0);
    asm volatile("s_waitcnt vmcnt(0)" ::: "memory");
    __builtin_amdgcn_s_barrier();
  }

  // Epilogue: hq = clamp(rint(relu(acc * ups[col]) / 64), 0, 127) -> i8
  float uc[4];
#pragma unroll
  for (int j = 0; j < 4; ++j)
    uc[j] = ups[bn * 256 + wn * 64 + j * 16 + lr] * 0.015625f;
#pragma unroll
  for (int i = 0; i < 4; ++i) {
    int gr = bm * 256 + wm * 64 + i * 16 + lg * 4;
#pragma unroll
    for (int j = 0; j < 4; ++j) {
      int gcol = bn * 256 + wn * 64 + j * 16 + lr;
#pragma unroll
      for (int r = 0; r < 4; ++r) {
        float q = rintf(fmaxf((float)acc[i][j][r] * uc[j], 0.f));
        q = fminf(q, 127.f);
        C[(size_t)(gr + r) * N + gcol] = (int8_t)(int)q;
      }
    }
  }
}

// ---------------- GEMM2: 256x128 i8, 3-buffer schedule (r15 verbatim) -------
__global__ __launch_bounds__(512, 2) void gemm2_i8_kernel(
    const int8_t* __restrict__ A, const int8_t* __restrict__ B,
    float* __restrict__ C, const float* __restrict__ sx,
    const float* __restrict__ dns, const float* __restrict__ oscale,
    int M, int N, int K) {
  constexpr int ABYTES = 256 * 128;     // 32768
  constexpr int BBYTES = 128 * 128;     // 16384
  constexpr int BUFB = ABYTES + BBYTES; // 49152
  extern __shared__ char smem[];

  const int nbn = N >> 7;
  const int bid = blockIdx.x;
  const int cpx = gridDim.x >> 3;
  const int swz = (bid & 7) * cpx + (bid >> 3);
  const int bm = swz / nbn, bn = swz % nbn;

  const int tid = threadIdx.x;
  const int lane = tid & 63;
  const int wv = tid >> 6;
  const int wm = wv >> 1, wn = wv & 1;  // 4 x 2 waves, 64x64 each
  const int lr = lane & 15, lg = lane >> 4;

  const int srow = tid >> 3;
  const int scolB = ((tid & 7) ^ (srow & 7)) << 4;
  const int8_t* aS = A + (size_t)(bm * 256 + srow) * K + scolB;
  const int8_t* bS = B + (size_t)(bn * 128 + srow) * K + scolB;
  const int ldsl = wv * 1024;

  i32x4 acc[4][4] = {};
  const int nt = K >> 7;

  auto STAGE = [&](int t, int q) {
    char* dA = smem + q * BUFB;
    char* dB = dA + ABYTES;
    const int8_t* a0 = aS + (size_t)t * 128;
    const int8_t* b0 = bS + (size_t)t * 128;
#pragma unroll
    for (int a = 0; a < 4; ++a)
      GLD16(a0 + (size_t)(a * 64) * K, dA + a * 8192 + ldsl);
#pragma unroll
    for (int b = 0; b < 2; ++b)
      GLD16(b0 + (size_t)(b * 64) * K, dB + b * 8192 + ldsl);
  };

  STAGE(0, 0);
  STAGE(1, 1);
  asm volatile("s_waitcnt vmcnt(6)" ::: "memory");
  __builtin_amdgcn_s_barrier();

  const int xorv = (lr & 7) << 4;
  int cur = 0;
  for (int t = 0; t < nt; ++t) {
    int nx = cur + 2; nx = (nx >= 3) ? nx - 3 : nx;
    if (t + 2 < nt) STAGE(t + 2, nx);

    const char* cA = smem + cur * BUFB;
    const char* cB = cA + ABYTES;
    i32x4 af[2][4], bfr[2][4];
#pragma unroll
    for (int ks = 0; ks < 2; ++ks) {
      int ko = ((ks << 6) + (lg << 4)) ^ xorv;
#pragma unroll
      for (int i = 0; i < 4; ++i)
        af[ks][i] = *(const i32x4*)(cA + ((wm * 64 + i * 16 + lr) << 7) + ko);
#pragma unroll
      for (int j = 0; j < 4; ++j)
        bfr[ks][j] = *(const i32x4*)(cB + ((wn * 64 + j * 16 + lr) << 7) + ko);
    }

    __builtin_amdgcn_s_setprio(1);
#pragma unroll
    for (int ks = 0; ks < 2; ++ks)
#pragma unroll
      for (int i = 0; i < 4; ++i)
#pragma unroll
        for (int j = 0; j < 4; ++j)
          acc[i][j] = __builtin_amdgcn_mfma_i32_16x16x64_i8(
              af[ks][i], bfr[ks][j], acc[i][j], 0, 0, 0);
    __builtin_amdgcn_s_setprio(0);

    if (t + 2 < nt) {
      asm volatile("s_waitcnt vmcnt(6)" ::: "memory");
    } else if (t + 1 < nt) {
      asm volatile("s_waitcnt vmcnt(0)" ::: "memory");
    }
    __builtin_amdgcn_s_barrier();
    cur = cur + 1; if (cur == 3) cur = 0;
  }

  float osc_v = oscale[0] * 64.f;
  float dc[4];
#pragma unroll
  for (int j = 0; j < 4; ++j)
    dc[j] = dns[bn * 128 + wn * 64 + j * 16 + lr] * osc_v;
#pragma unroll
  for (int i = 0; i < 4; ++i) {
    int gr = bm * 256 + wm * 64 + i * 16 + lg * 4;
    float4 shv = *(const float4*)(sx + gr);
#pragma unroll
    for (int j = 0; j < 4; ++j) {
      int gcol = bn * 128 + wn * 64 + j * 16 + lr;
      C[(size_t)(gr + 0) * N + gcol] = (float)acc[i][j][0] * shv.x * dc[j];
      C[(size_t)(gr + 1) * N + gcol] = (float)acc[i][j][1] * shv.y * dc[j];
      C[(size_t)(gr + 2) * N + gcol] = (float)acc[i][j][2] * shv.z * dc[j];
      C[(size_t)(gr + 3) * N + gcol] = (float)acc[i][j][3] * shv.w * dc[j];
    }
  }
}

extern "C" void kernel_launch(void* const* d_in, const int* in_sizes, int n_in,
                              void* d_out, int out_size, void* d_ws,
                              size_t ws_size, hipStream_t stream) {
  const float* x   = (const float*)d_in[0];
  const float* upw = (const float*)d_in[1];
  const float* dnw = (const float*)d_in[2];
  const float* ups = (const float*)d_in[3];
  const float* dns = (const float*)d_in[4];
  const float* osc = (const float*)d_in[5];
  float* out = (float*)d_out;

  char* ws = (char*)d_ws;
  int8_t* xq  = (int8_t*)(ws);              //  8 MB [4096][2048]
  int8_t* upq = (int8_t*)(ws + 8388608);    // 16 MB [8192][2048]
  int8_t* dnq = (int8_t*)(ws + 25165824);   // 16 MB [2048][8192]
  int8_t* hq  = (int8_t*)(ws + 41943040);   // 32 MB [4096][8192]
  float*  sx  = (float*)(ws + 75497472);    // 16 KB [4096]

  prep_kernel<<<8192, 256, 0, stream>>>(x, xq, sx, upw, upq, dnw, dnq);

  const int smem1 = 131072;  // 2 x 64 KB
  const int smem2 = 147456;  // 3 x 48 KB
  (void)hipFuncSetAttribute(reinterpret_cast<const void*>(gemm1_i8_kernel),
                            hipFuncAttributeMaxDynamicSharedMemorySize, smem1);
  (void)hipFuncSetAttribute(reinterpret_cast<const void*>(gemm2_i8_kernel),
                            hipFuncAttributeMaxDynamicSharedMemorySize, smem2);

  // GEMM1: hq = quant64(relu((xq @ upq^T) * ups)) -> i8. grid 16*32 = 512.
  gemm1_i8_kernel<<<(M_TOK / 256) * (DH / 256), 1024, smem1, stream>>>(
      xq, upq, hq, ups, M_TOK, DH, DM);
  // GEMM2: out = (hq @ dnq^T) * sx*64 * dns * osc -> f32. grid 16*16 = 256.
  gemm2_i8_kernel<<<(M_TOK / 256) * (DM / 128), 512, smem2, stream>>>(
      hq, dnq, out, sx, dns, osc, M_TOK, DM, DH);
}